// Round 1
// baseline (984.272 us; speedup 1.0000x reference)
//
#include <hip/hip_runtime.h>
#include <hip/hip_bf16.h>
#include <math.h>

// ---------------------------------------------------------------------------
// CustomTransformerEncoderLayer (linear attention, ELU+1 feature map)
// S=2048 B=8 D=1024 F=4096, fp32 in/out, bf16 MFMA internals.
//
// Pipeline (all on `stream`):
//   cast weights+src to bf16
//   Q = elu(src@wq^T+bq)+1 ; K = elu(...)+1 ; V = src@wv^T+bv      [gemm_bt]
//   Kt,Vt = per-batch transpose [B][D][S]                          [transpose]
//   KV[d,f] = sum_s Kt[d,s]*Vt[f,s]        (per batch)             [gemm_bt]
//   Mt[e,d] = sum_f wo[e,f]*KV[d,f]        (per batch)  (= (KV@wo^T)^T)
//   AO[s,b,e] = sum_d Q[s,b,d]*Mt[e,d] + bo[e] + src[s,b,e]        [gemm_bt]
//   x  = LN(AO; g1,be1)  -> fp32 X and bf16 Xb
//   h  = relu(Xb@w1^T+b1)  (4 row-chunks of 4096)                  [gemm_bt]
//   d_out = h@w2^T + b2 + X                                        [gemm_bt]
//   d_out = LN(d_out; g2,be2) in-place
// ---------------------------------------------------------------------------

typedef __attribute__((ext_vector_type(8))) short short8;
typedef __attribute__((ext_vector_type(4))) short short4_t;
typedef __attribute__((ext_vector_type(4))) float f32x4;

#define S_DIM 2048
#define B_DIM 8
#define D_DIM 1024
#define F_DIM 4096

__device__ __forceinline__ unsigned short f2bf(float f) {
  __hip_bfloat16 h = __float2bfloat16(f);
  return *reinterpret_cast<unsigned short*>(&h);
}

#define GLD16(gp, sp)                                              \
  __builtin_amdgcn_global_load_lds(                                \
      (const __attribute__((address_space(1))) void*)(gp),         \
      (__attribute__((address_space(3))) void*)(sp), 16, 0, 0)

// ---------------------------------------------------------------------------
// gemm_bt: C[i,j] = sum_k A[i,k] * B[j,k]   (A:[M,K] lda, B:[N,K] ldb)
// 128x128 tile, BK=32, 4 waves (2x2 of 64x64), mfma_f32_16x16x32_bf16.
// grid = (N/128, M/128, batch). Requires M%128==0, N%128==0, K%32==0.
// EPI: 0 none->bf16, 1 elu+1+bias->bf16, 2 bias->bf16, 3 relu+bias->bf16,
//      4 bias+fp32 residual -> fp32 out
// ---------------------------------------------------------------------------
template <int EPI>
__global__ __launch_bounds__(256, 2) void gemm_bt_kernel(
    const unsigned short* __restrict__ A, long lda, long sA,
    const unsigned short* __restrict__ B, long ldb, long sB,
    void* __restrict__ Cv, long ldc, long sC,
    const float* __restrict__ bias,
    const float* __restrict__ resid, long ldr, long sR, int K) {
  __shared__ short As[128 * 32];
  __shared__ short Bs[128 * 32];
  const int bz = blockIdx.z;
  const unsigned short* Ab = A + (long)bz * sA + (long)blockIdx.y * 128 * lda;
  const unsigned short* Bb = B + (long)bz * sB + (long)blockIdx.x * 128 * ldb;
  const int tid = threadIdx.x;
  const int w = tid >> 6, lane = tid & 63;
  const int srow = lane >> 2;        // 0..15: row within a 16-row LDS chunk
  const int scol = (lane & 3) * 8;   // 0/8/16/24: bf16 col of the 16B load
  const int wr = (w >> 1) * 64, wc = (w & 1) * 64;
  const int lr = lane & 15, kh = lane >> 4;

  f32x4 acc[4][4];
#pragma unroll
  for (int m = 0; m < 4; ++m)
#pragma unroll
    for (int n = 0; n < 4; ++n)
#pragma unroll
      for (int j = 0; j < 4; ++j) acc[m][n][j] = 0.f;

  // each wave stages two 16-row chunks of A and of B per K-step
  const unsigned short* ga0 = Ab + (long)(w * 16 + srow) * lda + scol;
  const unsigned short* ga1 = Ab + (long)(64 + w * 16 + srow) * lda + scol;
  const unsigned short* gb0 = Bb + (long)(w * 16 + srow) * ldb + scol;
  const unsigned short* gb1 = Bb + (long)(64 + w * 16 + srow) * ldb + scol;
  short* la0 = &As[(w * 16) * 32];
  short* la1 = &As[(64 + w * 16) * 32];
  short* lb0 = &Bs[(w * 16) * 32];
  short* lb1 = &Bs[(64 + w * 16) * 32];

  for (int k0 = 0; k0 < K; k0 += 32) {
    GLD16(ga0 + k0, la0);
    GLD16(ga1 + k0, la1);
    GLD16(gb0 + k0, lb0);
    GLD16(gb1 + k0, lb1);
    __syncthreads();  // compiler emits vmcnt(0) drain before barrier
    short8 af[4], bf[4];
#pragma unroll
    for (int m = 0; m < 4; ++m)
      af[m] = *(const short8*)&As[(wr + m * 16 + lr) * 32 + kh * 8];
#pragma unroll
    for (int n = 0; n < 4; ++n)
      bf[n] = *(const short8*)&Bs[(wc + n * 16 + lr) * 32 + kh * 8];
#pragma unroll
    for (int m = 0; m < 4; ++m)
#pragma unroll
      for (int n = 0; n < 4; ++n)
        acc[m][n] =
            __builtin_amdgcn_mfma_f32_16x16x32_bf16(af[m], bf[n], acc[m][n], 0, 0, 0);
    __syncthreads();
  }

  // C/D layout (m89-verified): col = lane&15, row = (lane>>4)*4 + reg
  const long gm0 = (long)blockIdx.y * 128 + wr;
  const long gn0 = (long)blockIdx.x * 128 + wc;
  if constexpr (EPI == 4) {
    float* C = (float*)Cv + (long)bz * sC;
    const float* R = resid + (long)bz * sR;
#pragma unroll
    for (int m = 0; m < 4; ++m)
#pragma unroll
      for (int n = 0; n < 4; ++n) {
        const long col = gn0 + n * 16 + lr;
        const float bcol = bias[col];
#pragma unroll
        for (int j = 0; j < 4; ++j) {
          const long row = gm0 + m * 16 + kh * 4 + j;
          C[row * ldc + col] = acc[m][n][j] + bcol + R[row * ldr + col];
        }
      }
  } else {
    unsigned short* C = (unsigned short*)Cv + (long)bz * sC;
#pragma unroll
    for (int m = 0; m < 4; ++m)
#pragma unroll
      for (int n = 0; n < 4; ++n) {
        const long col = gn0 + n * 16 + lr;
        float bcol = 0.f;
        if constexpr (EPI == 1 || EPI == 2 || EPI == 3) bcol = bias[col];
#pragma unroll
        for (int j = 0; j < 4; ++j) {
          const long row = gm0 + m * 16 + kh * 4 + j;
          float v = acc[m][n][j] + bcol;
          if constexpr (EPI == 1) v = (v > 0.f) ? (v + 1.f) : expf(v);  // elu+1
          if constexpr (EPI == 3) v = fmaxf(v, 0.f);                    // relu
          C[row * ldc + col] = f2bf(v);
        }
      }
  }
}

// ---------------------------------------------------------------------------
// transpose: in flat [S][B][D] bf16 -> out [B][D][S] bf16.
// grid (S/64, D/64, B), 256 threads, LDS 64x68 tile (pad 4 shorts: row stride
// 136B keeps b64 alignment and caps read conflicts at ~4-way).
// ---------------------------------------------------------------------------
__global__ __launch_bounds__(256) void transpose_kernel(
    const unsigned short* __restrict__ in, unsigned short* __restrict__ out) {
  __shared__ unsigned short t[64][68];
  const int b = blockIdx.z;
  const long s0 = (long)blockIdx.x * 64, d0 = (long)blockIdx.y * 64;
  const int tid = threadIdx.x;
  {
    const int r = tid >> 3, c = (tid & 7) * 8;  // r 0..31
#pragma unroll
    for (int it = 0; it < 2; ++it) {
      const int s = r + it * 32;
      const unsigned short* g = &in[(s0 + s) * (B_DIM * D_DIM) + (long)b * D_DIM + d0 + c];
      short4_t v0 = *(const short4_t*)g;
      short4_t v1 = *(const short4_t*)(g + 4);
      *(short4_t*)&t[s][c] = v0;
      *(short4_t*)&t[s][c + 4] = v1;
    }
  }
  __syncthreads();
  {
    const int d = tid >> 3, c = (tid & 7) * 8;  // d 0..31
#pragma unroll
    for (int it = 0; it < 2; ++it) {
      const int dd = d + it * 32;
      short8 v;
#pragma unroll
      for (int j = 0; j < 8; ++j) v[j] = (short)t[c + j][dd];
      *(short8*)&out[(long)b * ((long)D_DIM * S_DIM) + (d0 + dd) * S_DIM + s0 + c] = v;
    }
  }
}

// ---------------------------------------------------------------------------
// layernorm over last dim (1024). One block (256 thr) per row, 4 elems/thread.
// WRITE_BF16: additionally emit bf16 copy. Safe for in-place (outf == in).
// ---------------------------------------------------------------------------
template <int WRITE_BF16>
__global__ __launch_bounds__(256) void layernorm_kernel(
    const float* in, float* outf, unsigned short* __restrict__ outb,
    const float* __restrict__ gamma, const float* __restrict__ beta) {
  const long row = blockIdx.x;
  const float* x = in + row * D_DIM;
  const int tid = threadIdx.x;
  const int lane = tid & 63, w = tid >> 6;
  f32x4 v = *(const f32x4*)&x[tid * 4];
  float s = v[0] + v[1] + v[2] + v[3];
  float q = v[0] * v[0] + v[1] * v[1] + v[2] * v[2] + v[3] * v[3];
#pragma unroll
  for (int off = 32; off > 0; off >>= 1) {
    s += __shfl_down(s, off, 64);
    q += __shfl_down(q, off, 64);
  }
  __shared__ float red[8];
  if (lane == 0) { red[w] = s; red[w + 4] = q; }
  __syncthreads();
  s = red[0] + red[1] + red[2] + red[3];
  q = red[4] + red[5] + red[6] + red[7];
  const float mu = s * (1.f / D_DIM);
  const float var = q * (1.f / D_DIM) - mu * mu;
  const float rs = rsqrtf(var + 1e-5f);
  f32x4 g = *(const f32x4*)&gamma[tid * 4];
  f32x4 bb = *(const f32x4*)&beta[tid * 4];
  f32x4 o;
#pragma unroll
  for (int j = 0; j < 4; ++j) o[j] = (v[j] - mu) * rs * g[j] + bb[j];
  *(f32x4*)&outf[row * D_DIM + tid * 4] = o;
  if constexpr (WRITE_BF16) {
    short4_t ob;
#pragma unroll
    for (int j = 0; j < 4; ++j) ob[j] = (short)f2bf(o[j]);
    *(short4_t*)&outb[row * D_DIM + tid * 4] = ob;
  }
}

__global__ __launch_bounds__(256) void cast_kernel(
    const float* __restrict__ in, unsigned short* __restrict__ out, long n) {
  long i = ((long)blockIdx.x * 256 + threadIdx.x) * 8;
  if (i >= n) return;
  f32x4 a = *(const f32x4*)&in[i];
  f32x4 b = *(const f32x4*)&in[i + 4];
  short8 v;
#pragma unroll
  for (int j = 0; j < 4; ++j) v[j] = (short)f2bf(a[j]);
#pragma unroll
  for (int j = 0; j < 4; ++j) v[4 + j] = (short)f2bf(b[j]);
  *(short8*)&out[i] = v;
}

// ---------------------------------------------------------------------------
extern "C" void kernel_launch(void* const* d_in, const int* in_sizes, int n_in,
                              void* d_out, int out_size, void* d_ws, size_t ws_size,
                              hipStream_t stream) {
  const float* src = (const float*)d_in[0];
  const float* wq  = (const float*)d_in[1];
  const float* bq  = (const float*)d_in[2];
  const float* wk  = (const float*)d_in[3];
  const float* bk  = (const float*)d_in[4];
  const float* wv  = (const float*)d_in[5];
  const float* bv  = (const float*)d_in[6];
  const float* wo  = (const float*)d_in[7];
  const float* bo  = (const float*)d_in[8];
  const float* w1  = (const float*)d_in[9];
  const float* b1  = (const float*)d_in[10];
  const float* w2  = (const float*)d_in[11];
  const float* b2  = (const float*)d_in[12];
  const float* g1  = (const float*)d_in[13];
  const float* be1 = (const float*)d_in[14];
  const float* g2  = (const float*)d_in[15];
  const float* be2 = (const float*)d_in[16];

  const long MB = 1024L * 1024L;
  if (ws_size < 248 * MB) return;  // workspace plan needs 248 MB
  char* ws = (char*)d_ws;
  // persistent bf16 weights
  unsigned short* wqb  = (unsigned short*)(ws + 0 * MB);    // 2 MB
  unsigned short* wkb  = (unsigned short*)(ws + 2 * MB);    // 2
  unsigned short* wvb  = (unsigned short*)(ws + 4 * MB);    // 2
  unsigned short* wob  = (unsigned short*)(ws + 6 * MB);    // 2
  unsigned short* w1b  = (unsigned short*)(ws + 8 * MB);    // 8
  unsigned short* w2b  = (unsigned short*)(ws + 16 * MB);   // 8
  unsigned short* srcb = (unsigned short*)(ws + 24 * MB);   // 32 (dead after V)
  unsigned short* Qb   = (unsigned short*)(ws + 56 * MB);   // 32 (dead after AO)
  unsigned short* Kb   = (unsigned short*)(ws + 88 * MB);   // 32 (dead after transpose)
  unsigned short* Vb   = (unsigned short*)(ws + 120 * MB);  // 32 (dead after transpose)
  unsigned short* Kt   = (unsigned short*)(ws + 152 * MB);  // 32 (dead after KV)
  unsigned short* Vt   = (unsigned short*)(ws + 184 * MB);  // 32 (dead after KV)
  unsigned short* KVm  = (unsigned short*)(ws + 216 * MB);  // 16 (dead after Mt)
  unsigned short* Mt   = (unsigned short*)(ws + 232 * MB);  // 16 (dead after AO)
  float*          AO   = (float*)(ws + 88 * MB);            // 64, reuse Kb+Vb
  float*          X    = (float*)(ws + 152 * MB);           // 64, reuse Kt+Vt
  unsigned short* Xb   = (unsigned short*)(ws + 24 * MB);   // 32, reuse srcb
  unsigned short* H    = (unsigned short*)(ws + 216 * MB);  // 32, reuse KV+Mt

  const dim3 blk(256);
  // casts
  cast_kernel<<<dim3(512), blk, 0, stream>>>(wq, wqb, 1048576);
  cast_kernel<<<dim3(512), blk, 0, stream>>>(wk, wkb, 1048576);
  cast_kernel<<<dim3(512), blk, 0, stream>>>(wv, wvb, 1048576);
  cast_kernel<<<dim3(512), blk, 0, stream>>>(wo, wob, 1048576);
  cast_kernel<<<dim3(2048), blk, 0, stream>>>(w1, w1b, 4194304);
  cast_kernel<<<dim3(2048), blk, 0, stream>>>(w2, w2b, 4194304);
  cast_kernel<<<dim3(8192), blk, 0, stream>>>(src, srcb, 16777216);

  // Q/K/V projections: [16384,1024] @ [1024,1024]^T
  gemm_bt_kernel<1><<<dim3(8, 128, 1), blk, 0, stream>>>(
      srcb, 1024, 0, wqb, 1024, 0, Qb, 1024, 0, bq, nullptr, 0, 0, 1024);
  gemm_bt_kernel<1><<<dim3(8, 128, 1), blk, 0, stream>>>(
      srcb, 1024, 0, wkb, 1024, 0, Kb, 1024, 0, bk, nullptr, 0, 0, 1024);
  gemm_bt_kernel<2><<<dim3(8, 128, 1), blk, 0, stream>>>(
      srcb, 1024, 0, wvb, 1024, 0, Vb, 1024, 0, bv, nullptr, 0, 0, 1024);

  // per-batch transposes -> [B][D][S]
  transpose_kernel<<<dim3(32, 16, 8), blk, 0, stream>>>(Kb, Kt);
  transpose_kernel<<<dim3(32, 16, 8), blk, 0, stream>>>(Vb, Vt);

  // KV[d,f] = sum_s Kt[d,s]*Vt[f,s]  (M=N=1024, K=2048, batch 8)
  gemm_bt_kernel<0><<<dim3(8, 8, 8), blk, 0, stream>>>(
      Kt, 2048, 2097152, Vt, 2048, 2097152, KVm, 1024, 1048576,
      nullptr, nullptr, 0, 0, 2048);
  // Mt[e,d] = sum_f wo[e,f]*KV[d,f]  (M=N=1024, K=1024, batch 8)
  gemm_bt_kernel<0><<<dim3(8, 8, 8), blk, 0, stream>>>(
      wob, 1024, 0, KVm, 1024, 1048576, Mt, 1024, 1048576,
      nullptr, nullptr, 0, 0, 1024);
  // AO[s,b,e] = sum_d Q[s,b,d]*Mt[e,d] + bo[e] + src  (M=2048/batch, N=1024)
  gemm_bt_kernel<4><<<dim3(8, 16, 8), blk, 0, stream>>>(
      Qb, 8192, 1024, Mt, 1024, 1048576, AO, 8192, 1024,
      bo, src, 8192, 1024, 1024);

  // x = LN(AO)
  layernorm_kernel<1><<<dim3(16384), blk, 0, stream>>>(AO, X, Xb, g1, be1);

  // FFN in 4 row-chunks of 4096 (H buffer reuse)
  for (int c = 0; c < 4; ++c) {
    gemm_bt_kernel<3><<<dim3(32, 32, 1), blk, 0, stream>>>(
        Xb + (long)c * 4194304, 1024, 0, w1b, 1024, 0, H, 4096, 0,
        b1, nullptr, 0, 0, 1024);
    gemm_bt_kernel<4><<<dim3(8, 32, 1), blk, 0, stream>>>(
        H, 4096, 0, w2b, 4096, 0, (float*)d_out + (long)c * 4194304, 1024, 0,
        b2, X + (long)c * 4194304, 1024, 0, 4096);
  }

  // final LN in-place on d_out
  layernorm_kernel<0><<<dim3(16384), blk, 0, stream>>>(
      (float*)d_out, (float*)d_out, nullptr, g2, be2);
}

// Round 2
// 744.094 us; speedup vs baseline: 1.3228x; 1.3228x over previous
//
#include <hip/hip_runtime.h>
#include <hip/hip_bf16.h>
#include <math.h>

// ---------------------------------------------------------------------------
// CustomTransformerEncoderLayer (linear attention, ELU+1 feature map)
// S=2048 B=8 D=1024 F=4096, fp32 in/out, bf16 MFMA internals.
//
// Round 2: un-chunked FFN (full M=16384 -> FFN2 grid 1024 blocks = 4/CU,
// was 1/CU latency-bound at 119us x4) + T1 XCD-aware block swizzle in the
// GEMM (A-panel L2 reuse within an XCD). Workspace re-planned to 240 MB
// peak so H (128 MB) fits contiguously.
// ---------------------------------------------------------------------------

typedef __attribute__((ext_vector_type(8))) short short8;
typedef __attribute__((ext_vector_type(4))) short short4_t;
typedef __attribute__((ext_vector_type(4))) float f32x4;

#define S_DIM 2048
#define B_DIM 8
#define D_DIM 1024
#define F_DIM 4096

__device__ __forceinline__ unsigned short f2bf(float f) {
  __hip_bfloat16 h = __float2bfloat16(f);
  return *reinterpret_cast<unsigned short*>(&h);
}

#define GLD16(gp, sp)                                              \
  __builtin_amdgcn_global_load_lds(                                \
      (const __attribute__((address_space(1))) void*)(gp),         \
      (__attribute__((address_space(3))) void*)(sp), 16, 0, 0)

// ---------------------------------------------------------------------------
// gemm_bt: C[i,j] = sum_k A[i,k] * B[j,k]   (A:[M,K] lda, B:[N,K] ldb)
// 128x128 tile, BK=32, 4 waves (2x2 of 64x64), mfma_f32_16x16x32_bf16.
// grid = (N/128, M/128, batch). Requires M%128==0, N%128==0, K%32==0,
// and gridDim.x*gridDim.y % 8 == 0 (XCD swizzle bijectivity).
// EPI: 0 none->bf16, 1 elu+1+bias->bf16, 2 bias->bf16, 3 relu+bias->bf16,
//      4 bias+fp32 residual -> fp32 out
// ---------------------------------------------------------------------------
template <int EPI>
__global__ __launch_bounds__(256, 2) void gemm_bt_kernel(
    const unsigned short* __restrict__ A, long lda, long sA,
    const unsigned short* __restrict__ B, long ldb, long sB,
    void* __restrict__ Cv, long ldc, long sC,
    const float* __restrict__ bias,
    const float* __restrict__ resid, long ldr, long sR, int K) {
  __shared__ short As[128 * 32];
  __shared__ short Bs[128 * 32];
  // T1: XCD-aware swizzle. orig%8 is this block's XCD (round-robin dispatch);
  // give each XCD a contiguous chunk of logical tile ids -> A-panel reuse in L2.
  const int gx = gridDim.x;
  const int nwg = gx * gridDim.y;
  const int orig = blockIdx.y * gx + blockIdx.x;
  const int cpx = nwg >> 3;
  const int wgid = (orig & 7) * cpx + (orig >> 3);
  const int bx = wgid % gx;
  const int by = wgid / gx;

  const int bz = blockIdx.z;
  const unsigned short* Ab = A + (long)bz * sA + (long)by * 128 * lda;
  const unsigned short* Bb = B + (long)bz * sB + (long)bx * 128 * ldb;
  const int tid = threadIdx.x;
  const int w = tid >> 6, lane = tid & 63;
  const int srow = lane >> 2;        // 0..15: row within a 16-row LDS chunk
  const int scol = (lane & 3) * 8;   // 0/8/16/24: bf16 col of the 16B load
  const int wr = (w >> 1) * 64, wc = (w & 1) * 64;
  const int lr = lane & 15, kh = lane >> 4;

  f32x4 acc[4][4];
#pragma unroll
  for (int m = 0; m < 4; ++m)
#pragma unroll
    for (int n = 0; n < 4; ++n)
#pragma unroll
      for (int j = 0; j < 4; ++j) acc[m][n][j] = 0.f;

  // each wave stages two 16-row chunks of A and of B per K-step
  const unsigned short* ga0 = Ab + (long)(w * 16 + srow) * lda + scol;
  const unsigned short* ga1 = Ab + (long)(64 + w * 16 + srow) * lda + scol;
  const unsigned short* gb0 = Bb + (long)(w * 16 + srow) * ldb + scol;
  const unsigned short* gb1 = Bb + (long)(64 + w * 16 + srow) * ldb + scol;
  short* la0 = &As[(w * 16) * 32];
  short* la1 = &As[(64 + w * 16) * 32];
  short* lb0 = &Bs[(w * 16) * 32];
  short* lb1 = &Bs[(64 + w * 16) * 32];

  for (int k0 = 0; k0 < K; k0 += 32) {
    GLD16(ga0 + k0, la0);
    GLD16(ga1 + k0, la1);
    GLD16(gb0 + k0, lb0);
    GLD16(gb1 + k0, lb1);
    __syncthreads();  // compiler emits vmcnt(0) drain before barrier
    short8 af[4], bf[4];
#pragma unroll
    for (int m = 0; m < 4; ++m)
      af[m] = *(const short8*)&As[(wr + m * 16 + lr) * 32 + kh * 8];
#pragma unroll
    for (int n = 0; n < 4; ++n)
      bf[n] = *(const short8*)&Bs[(wc + n * 16 + lr) * 32 + kh * 8];
#pragma unroll
    for (int m = 0; m < 4; ++m)
#pragma unroll
      for (int n = 0; n < 4; ++n)
        acc[m][n] =
            __builtin_amdgcn_mfma_f32_16x16x32_bf16(af[m], bf[n], acc[m][n], 0, 0, 0);
    __syncthreads();
  }

  // C/D layout (m89-verified): col = lane&15, row = (lane>>4)*4 + reg
  const long gm0 = (long)by * 128 + wr;
  const long gn0 = (long)bx * 128 + wc;
  if constexpr (EPI == 4) {
    float* C = (float*)Cv + (long)bz * sC;
    const float* R = resid + (long)bz * sR;
#pragma unroll
    for (int m = 0; m < 4; ++m)
#pragma unroll
      for (int n = 0; n < 4; ++n) {
        const long col = gn0 + n * 16 + lr;
        const float bcol = bias[col];
#pragma unroll
        for (int j = 0; j < 4; ++j) {
          const long row = gm0 + m * 16 + kh * 4 + j;
          C[row * ldc + col] = acc[m][n][j] + bcol + R[row * ldr + col];
        }
      }
  } else {
    unsigned short* C = (unsigned short*)Cv + (long)bz * sC;
#pragma unroll
    for (int m = 0; m < 4; ++m)
#pragma unroll
      for (int n = 0; n < 4; ++n) {
        const long col = gn0 + n * 16 + lr;
        float bcol = 0.f;
        if constexpr (EPI == 1 || EPI == 2 || EPI == 3) bcol = bias[col];
#pragma unroll
        for (int j = 0; j < 4; ++j) {
          const long row = gm0 + m * 16 + kh * 4 + j;
          float v = acc[m][n][j] + bcol;
          if constexpr (EPI == 1) v = (v > 0.f) ? (v + 1.f) : expf(v);  // elu+1
          if constexpr (EPI == 3) v = fmaxf(v, 0.f);                    // relu
          C[row * ldc + col] = f2bf(v);
        }
      }
  }
}

// ---------------------------------------------------------------------------
// transpose: in flat [S][B][D] bf16 -> out [B][D][S] bf16.
// grid (S/64, D/64, B), 256 threads, LDS 64x68 tile.
// ---------------------------------------------------------------------------
__global__ __launch_bounds__(256) void transpose_kernel(
    const unsigned short* __restrict__ in, unsigned short* __restrict__ out) {
  __shared__ unsigned short t[64][68];
  const int b = blockIdx.z;
  const long s0 = (long)blockIdx.x * 64, d0 = (long)blockIdx.y * 64;
  const int tid = threadIdx.x;
  {
    const int r = tid >> 3, c = (tid & 7) * 8;  // r 0..31
#pragma unroll
    for (int it = 0; it < 2; ++it) {
      const int s = r + it * 32;
      const unsigned short* g = &in[(s0 + s) * (B_DIM * D_DIM) + (long)b * D_DIM + d0 + c];
      short4_t v0 = *(const short4_t*)g;
      short4_t v1 = *(const short4_t*)(g + 4);
      *(short4_t*)&t[s][c] = v0;
      *(short4_t*)&t[s][c + 4] = v1;
    }
  }
  __syncthreads();
  {
    const int d = tid >> 3, c = (tid & 7) * 8;  // d 0..31
#pragma unroll
    for (int it = 0; it < 2; ++it) {
      const int dd = d + it * 32;
      short8 v;
#pragma unroll
      for (int j = 0; j < 8; ++j) v[j] = (short)t[c + j][dd];
      *(short8*)&out[(long)b * ((long)D_DIM * S_DIM) + (d0 + dd) * S_DIM + s0 + c] = v;
    }
  }
}

// ---------------------------------------------------------------------------
// layernorm over last dim (1024). One block (256 thr) per row, 4 elems/thread.
// ---------------------------------------------------------------------------
template <int WRITE_BF16>
__global__ __launch_bounds__(256) void layernorm_kernel(
    const float* in, float* outf, unsigned short* __restrict__ outb,
    const float* __restrict__ gamma, const float* __restrict__ beta) {
  const long row = blockIdx.x;
  const float* x = in + row * D_DIM;
  const int tid = threadIdx.x;
  const int lane = tid & 63, w = tid >> 6;
  f32x4 v = *(const f32x4*)&x[tid * 4];
  float s = v[0] + v[1] + v[2] + v[3];
  float q = v[0] * v[0] + v[1] * v[1] + v[2] * v[2] + v[3] * v[3];
#pragma unroll
  for (int off = 32; off > 0; off >>= 1) {
    s += __shfl_down(s, off, 64);
    q += __shfl_down(q, off, 64);
  }
  __shared__ float red[8];
  if (lane == 0) { red[w] = s; red[w + 4] = q; }
  __syncthreads();
  s = red[0] + red[1] + red[2] + red[3];
  q = red[4] + red[5] + red[6] + red[7];
  const float mu = s * (1.f / D_DIM);
  const float var = q * (1.f / D_DIM) - mu * mu;
  const float rs = rsqrtf(var + 1e-5f);
  f32x4 g = *(const f32x4*)&gamma[tid * 4];
  f32x4 bb = *(const f32x4*)&beta[tid * 4];
  f32x4 o;
#pragma unroll
  for (int j = 0; j < 4; ++j) o[j] = (v[j] - mu) * rs * g[j] + bb[j];
  *(f32x4*)&outf[row * D_DIM + tid * 4] = o;
  if constexpr (WRITE_BF16) {
    short4_t ob;
#pragma unroll
    for (int j = 0; j < 4; ++j) ob[j] = (short)f2bf(o[j]);
    *(short4_t*)&outb[row * D_DIM + tid * 4] = ob;
  }
}

__global__ __launch_bounds__(256) void cast_kernel(
    const float* __restrict__ in, unsigned short* __restrict__ out, long n) {
  long i = ((long)blockIdx.x * 256 + threadIdx.x) * 8;
  if (i >= n) return;
  f32x4 a = *(const f32x4*)&in[i];
  f32x4 b = *(const f32x4*)&in[i + 4];
  short8 v;
#pragma unroll
  for (int j = 0; j < 4; ++j) v[j] = (short)f2bf(a[j]);
#pragma unroll
  for (int j = 0; j < 4; ++j) v[4 + j] = (short)f2bf(b[j]);
  *(short8*)&out[i] = v;
}

// ---------------------------------------------------------------------------
// Workspace plan (MB offsets; 240 MB peak, all overlaps verified vs stream
// order -- each region is reused only after its previous tenant's last read):
//   0-8    w1b        (persist)
//   8-16   w2b        (persist)
//   16-80  X fp32     (LN1 -> FFN2 residual)  | early: Vt 16-48, KVm 48-64,
//                                             |        Mt 64-80
//   80-112 Xb bf16    (LN1 -> FFN1 A)
//   112-240 H bf16    (FFN1 -> FFN2 A)        | early: wq/wk/wv/wo b 112-120,
//                                             |  srcb->Kt 120-152, Qb 152-184,
//                                             |  Kb 184-216, Vb 216-248,
//                                             |  AO fp32 184-248
// ---------------------------------------------------------------------------
extern "C" void kernel_launch(void* const* d_in, const int* in_sizes, int n_in,
                              void* d_out, int out_size, void* d_ws, size_t ws_size,
                              hipStream_t stream) {
  const float* src = (const float*)d_in[0];
  const float* wq  = (const float*)d_in[1];
  const float* bq  = (const float*)d_in[2];
  const float* wk  = (const float*)d_in[3];
  const float* bk  = (const float*)d_in[4];
  const float* wv  = (const float*)d_in[5];
  const float* bv  = (const float*)d_in[6];
  const float* wo  = (const float*)d_in[7];
  const float* bo  = (const float*)d_in[8];
  const float* w1  = (const float*)d_in[9];
  const float* b1  = (const float*)d_in[10];
  const float* w2  = (const float*)d_in[11];
  const float* b2  = (const float*)d_in[12];
  const float* g1  = (const float*)d_in[13];
  const float* be1 = (const float*)d_in[14];
  const float* g2  = (const float*)d_in[15];
  const float* be2 = (const float*)d_in[16];

  const long MB = 1024L * 1024L;
  if (ws_size < 248 * MB) return;
  char* ws = (char*)d_ws;
  unsigned short* w1b  = (unsigned short*)(ws + 0 * MB);
  unsigned short* w2b  = (unsigned short*)(ws + 8 * MB);
  float*          X    = (float*)(ws + 16 * MB);
  unsigned short* Xb   = (unsigned short*)(ws + 80 * MB);
  unsigned short* H    = (unsigned short*)(ws + 112 * MB);
  // early-phase tenants
  unsigned short* wqb  = (unsigned short*)(ws + 112 * MB);
  unsigned short* wkb  = (unsigned short*)(ws + 114 * MB);
  unsigned short* wvb  = (unsigned short*)(ws + 116 * MB);
  unsigned short* wob  = (unsigned short*)(ws + 118 * MB);
  unsigned short* srcb = (unsigned short*)(ws + 120 * MB);
  unsigned short* Kt   = (unsigned short*)(ws + 120 * MB);  // after srcb dead
  unsigned short* Vt   = (unsigned short*)(ws + 16 * MB);
  unsigned short* KVm  = (unsigned short*)(ws + 48 * MB);
  unsigned short* Mt   = (unsigned short*)(ws + 64 * MB);
  unsigned short* Qb   = (unsigned short*)(ws + 152 * MB);
  unsigned short* Kb   = (unsigned short*)(ws + 184 * MB);
  unsigned short* Vb   = (unsigned short*)(ws + 216 * MB);
  float*          AO   = (float*)(ws + 184 * MB);           // after Kb/Vb dead

  const dim3 blk(256);
  // casts
  cast_kernel<<<dim3(512), blk, 0, stream>>>(wq, wqb, 1048576);
  cast_kernel<<<dim3(512), blk, 0, stream>>>(wk, wkb, 1048576);
  cast_kernel<<<dim3(512), blk, 0, stream>>>(wv, wvb, 1048576);
  cast_kernel<<<dim3(512), blk, 0, stream>>>(wo, wob, 1048576);
  cast_kernel<<<dim3(2048), blk, 0, stream>>>(w1, w1b, 4194304);
  cast_kernel<<<dim3(2048), blk, 0, stream>>>(w2, w2b, 4194304);
  cast_kernel<<<dim3(8192), blk, 0, stream>>>(src, srcb, 16777216);

  // Q/K/V projections: [16384,1024] @ [1024,1024]^T
  gemm_bt_kernel<1><<<dim3(8, 128, 1), blk, 0, stream>>>(
      srcb, 1024, 0, wqb, 1024, 0, Qb, 1024, 0, bq, nullptr, 0, 0, 1024);
  gemm_bt_kernel<1><<<dim3(8, 128, 1), blk, 0, stream>>>(
      srcb, 1024, 0, wkb, 1024, 0, Kb, 1024, 0, bk, nullptr, 0, 0, 1024);
  gemm_bt_kernel<2><<<dim3(8, 128, 1), blk, 0, stream>>>(
      srcb, 1024, 0, wvb, 1024, 0, Vb, 1024, 0, bv, nullptr, 0, 0, 1024);

  // per-batch transposes -> [B][D][S]
  transpose_kernel<<<dim3(32, 16, 8), blk, 0, stream>>>(Kb, Kt);
  transpose_kernel<<<dim3(32, 16, 8), blk, 0, stream>>>(Vb, Vt);

  // KV[d,f] = sum_s Kt[d,s]*Vt[f,s]  (M=N=1024, K=2048, batch 8)
  gemm_bt_kernel<0><<<dim3(8, 8, 8), blk, 0, stream>>>(
      Kt, 2048, 2097152, Vt, 2048, 2097152, KVm, 1024, 1048576,
      nullptr, nullptr, 0, 0, 2048);
  // Mt[e,d] = sum_f wo[e,f]*KV[d,f]  (M=N=1024, K=1024, batch 8)
  gemm_bt_kernel<0><<<dim3(8, 8, 8), blk, 0, stream>>>(
      wob, 1024, 0, KVm, 1024, 1048576, Mt, 1024, 1048576,
      nullptr, nullptr, 0, 0, 1024);
  // AO[s,b,e] = sum_d Q[s,b,d]*Mt[e,d] + bo[e] + src  (M=2048/batch, N=1024)
  gemm_bt_kernel<4><<<dim3(8, 16, 8), blk, 0, stream>>>(
      Qb, 8192, 1024, Mt, 1024, 1048576, AO, 8192, 1024,
      bo, src, 8192, 1024, 1024);

  // x = LN(AO)
  layernorm_kernel<1><<<dim3(16384), blk, 0, stream>>>(AO, X, Xb, g1, be1);

  // FFN, full M=16384
  gemm_bt_kernel<3><<<dim3(32, 128, 1), blk, 0, stream>>>(
      Xb, 1024, 0, w1b, 1024, 0, H, 4096, 0, b1, nullptr, 0, 0, 1024);
  gemm_bt_kernel<4><<<dim3(8, 128, 1), blk, 0, stream>>>(
      H, 4096, 0, w2b, 4096, 0, (float*)d_out, 1024, 0,
      b2, X, 1024, 0, 4096);

  // final LN in-place on d_out
  layernorm_kernel<0><<<dim3(16384), blk, 0, stream>>>(
      (float*)d_out, (float*)d_out, nullptr, g2, be2);
}

// Round 3
// 646.698 us; speedup vs baseline: 1.5220x; 1.1506x over previous
//
#include <hip/hip_runtime.h>
#include <hip/hip_bf16.h>
#include <math.h>

// ---------------------------------------------------------------------------
// CustomTransformerEncoderLayer (linear attention, ELU+1 feature map)
// S=2048 B=8 D=1024 F=4096, fp32 in/out, bf16 MFMA internals.
//
// Round 3: 256x256-tile 8-phase GEMM (T1 XCD swizzle + T2 LDS XOR swizzle +
// T3/T4 8-phase counted-vmcnt pipeline + T5 setprio) for QKV/AO/FFN1/FFN2.
// KV/Mt stay on the 128^2 2-phase kernel (grid too small for 256^2).
// ---------------------------------------------------------------------------

typedef __attribute__((ext_vector_type(8))) short short8;
typedef __attribute__((ext_vector_type(4))) short short4_t;
typedef __attribute__((ext_vector_type(4))) float f32x4;

#define S_DIM 2048
#define B_DIM 8
#define D_DIM 1024
#define F_DIM 4096

__device__ __forceinline__ unsigned short f2bf(float f) {
  __hip_bfloat16 h = __float2bfloat16(f);
  return *reinterpret_cast<unsigned short*>(&h);
}

#define GLD16(gp, sp)                                              \
  __builtin_amdgcn_global_load_lds(                                \
      (const __attribute__((address_space(1))) void*)(gp),         \
      (__attribute__((address_space(3))) void*)(sp), 16, 0, 0)

#define BAR()                                  \
  do {                                         \
    asm volatile("" ::: "memory");             \
    __builtin_amdgcn_s_barrier();              \
    asm volatile("" ::: "memory");             \
  } while (0)
#define WAITVM4() asm volatile("s_waitcnt vmcnt(4)" ::: "memory")
#define WAITVM0() asm volatile("s_waitcnt vmcnt(0)" ::: "memory")
#define SCHED_FENCE() __builtin_amdgcn_sched_barrier(0)

// ---------------------------------------------------------------------------
// gemm256: C[i,j] = sum_k A[i,k]*B[j,k], BM=BN=256, BK=64, 512 thr (8 waves
// 2Mx4N), per-wave 128x64 output. 8-phase K-loop, double-buffered 128KiB LDS,
// counted vmcnt(4), LDS chunk^row XOR swizzle (conflict-free ds_read_b128).
// Requires M%256==0, N%256==0, K%128==0, gridDim.x*gridDim.y%8==0.
// LDS map (bytes, per buf b at b*65536): A_h at h*16384, B_nh at 32768+nh*16384.
// Each 16KiB region: 128 local rows x 128B; slot(row r, chunk c') holds global
// chunk c = c' ^ (r&7)  (16B chunks).
// EPI: 1 elu+1+bias->bf16, 2 bias->bf16, 3 relu+bias->bf16, 4 bias+residual->f32
// ---------------------------------------------------------------------------
template <int EPI>
__global__ __launch_bounds__(512, 2) void gemm256_kernel(
    const unsigned short* __restrict__ A, long lda, long sA,
    const unsigned short* __restrict__ B, long ldb, long sB,
    void* __restrict__ Cv, long ldc, long sC,
    const float* __restrict__ bias,
    const float* __restrict__ resid, long ldr, long sR, int K) {
  __shared__ short lds[65536];  // 128 KiB
  // T1 XCD swizzle
  const int gx = gridDim.x;
  const int nwg = gx * gridDim.y;
  const int orig = blockIdx.y * gx + blockIdx.x;
  const int cpx = nwg >> 3;
  const int wgid = (orig & 7) * cpx + (orig >> 3);
  const int bx = wgid % gx, by = wgid / gx;
  const int bz = blockIdx.z;
  const unsigned short* Ablk = A + (long)bz * sA + (long)by * 256 * lda;
  const unsigned short* Bblk = B + (long)bz * sB + (long)bx * 256 * ldb;

  const int tid = threadIdx.x;
  const int w = tid >> 6, lane = tid & 63;
  const int wm = w >> 2, wn = w & 3;
  const int lr = lane & 15, kh = lane >> 4;

  // --- staging geometry (2 global_load_lds per thread per half-tile) ---
  // load l in {0,1}: LDS slot s = (l*8+w)*64+lane -> local row r=s>>3,
  // swizzled chunk c' = lane&7; source chunk c = c' ^ (r&7) = (lane&7)^(lane>>3)
  const int sr = w * 8 + (lane >> 3);              // l=0 local row (0..63)
  const int sc = ((lane & 7) ^ (lane >> 3)) * 8;   // source col in shorts
  // A: local row r -> global M row (r>>6)*128 + h*64 + (r&63)
  const long aoff0 = (long)sr * lda + sc;          // l=0: rows 0..63
  const long aoff1 = (long)(128 + sr) * lda + sc;  // l=1: rows 128..191 (pre h)
  // B: local row r -> global N row (r>>5)*64 + nh*32 + (r&31)
  const int br0 = sr + ((sr >> 5) << 5);
  const int br1 = (64 + sr) + (((64 + sr) >> 5) << 5);
  const long boff0 = (long)br0 * ldb + sc;
  const long boff1 = (long)br1 * ldb + sc;
  const int dst0 = w * 1024;          // LDS byte offset within region, l=0
  const int dst1 = (8 + w) * 1024;    // l=1

#define STAGE_A(bufOff, h, kt)                                                \
  do {                                                                        \
    const unsigned short* _g = Ablk + (long)(h) * 64 * lda + (long)(kt) * 64; \
    GLD16(_g + aoff0, (char*)lds + (bufOff) + (h)*16384 + dst0);              \
    GLD16(_g + aoff1, (char*)lds + (bufOff) + (h)*16384 + dst1);              \
  } while (0)
#define STAGE_B(bufOff, nh, kt)                                               \
  do {                                                                        \
    const unsigned short* _g = Bblk + (long)(nh) * 32 * ldb + (long)(kt) * 64;\
    GLD16(_g + boff0, (char*)lds + (bufOff) + 32768 + (nh)*16384 + dst0);     \
    GLD16(_g + boff1, (char*)lds + (bufOff) + 32768 + (nh)*16384 + dst1);     \
  } while (0)

  // --- fragment-read geometry ---
  // A frag (h,m,ks): local row r = wm*64+m*16+lr, byte = r*128 + ((ks*4+kh)^(lr&7))*16
  const int chk0 = ((kh ^ (lr & 7)) << 4);
  const int chk1 = (((4 + kh) ^ (lr & 7)) << 4);
  const int aRdBase = (wm * 64 + lr) * 128;
  const int bRdBase = (wn * 32 + lr) * 128;

  short8 af[4][2], b0r[2][2], b1r[2][2];
  f32x4 acc[8][4];
#pragma unroll
  for (int m = 0; m < 8; ++m)
#pragma unroll
    for (int n = 0; n < 4; ++n)
#pragma unroll
      for (int j = 0; j < 4; ++j) acc[m][n][j] = 0.f;

#define LDA_H(bufOff, h)                                                     \
  do {                                                                       \
    const char* _p = (const char*)lds + (bufOff) + (h)*16384 + aRdBase;      \
    _Pragma("unroll") for (int m = 0; m < 4; ++m) {                          \
      af[m][0] = *(const short8*)(_p + m * 2048 + chk0);                     \
      af[m][1] = *(const short8*)(_p + m * 2048 + chk1);                     \
    }                                                                        \
  } while (0)
#define LDB_H(dst, bufOff, nh)                                               \
  do {                                                                       \
    const char* _p = (const char*)lds + (bufOff) + 32768 + (nh)*16384 + bRdBase; \
    _Pragma("unroll") for (int n = 0; n < 2; ++n) {                          \
      dst[n][0] = *(const short8*)(_p + n * 2048 + chk0);                    \
      dst[n][1] = *(const short8*)(_p + n * 2048 + chk1);                    \
    }                                                                        \
  } while (0)
#define MFMA_Q(mh, nh, bset)                                                 \
  do {                                                                       \
    SCHED_FENCE();                                                           \
    __builtin_amdgcn_s_setprio(1);                                           \
    _Pragma("unroll") for (int m = 0; m < 4; ++m)                            \
    _Pragma("unroll") for (int n = 0; n < 2; ++n)                            \
    _Pragma("unroll") for (int ks = 0; ks < 2; ++ks)                         \
      acc[(mh)*4 + m][(nh)*2 + n] = __builtin_amdgcn_mfma_f32_16x16x32_bf16( \
          af[m][ks], bset[n][ks], acc[(mh)*4 + m][(nh)*2 + n], 0, 0, 0);     \
    __builtin_amdgcn_s_setprio(0);                                           \
    SCHED_FENCE();                                                           \
  } while (0)

  const int T = K >> 6;  // K-tiles of 64; T even (K%128==0)
  // prologue: tile0 (all 4 halves -> buf0) + tile1 A0,B1 -> buf1
  STAGE_A(0, 0, 0); STAGE_B(0, 0, 0); STAGE_A(0, 1, 0); STAGE_B(0, 1, 0);
  STAGE_A(65536, 0, 1); STAGE_B(65536, 1, 1);
  WAITVM4();  // tile0 fully landed (tile1's 2 half-tiles may be in flight)
  BAR();

  for (int i = 0; i < (T >> 1); ++i) {
    const int kt1 = 2 * i + 1;
    const int ktn0 = (2 * i + 2 < T) ? (2 * i + 2) : (T - 1);  // clamp: tail
    const int ktn1 = (2 * i + 3 < T) ? (2 * i + 3) : (T - 1);  // stages land
    // ph0: tile 2i quadrant (mh0,nh0)                         // in dead LDS
    LDA_H(0, 0); LDB_H(b0r, 0, 0); STAGE_A(65536, 1, kt1);
    BAR(); MFMA_Q(0, 0, b0r); BAR();
    // ph1: (mh0,nh1)
    LDB_H(b1r, 0, 1); STAGE_B(65536, 0, kt1);
    BAR(); MFMA_Q(0, 1, b1r); BAR();
    // ph2: (mh1,nh1)
    LDA_H(0, 1); STAGE_A(0, 0, ktn0);
    BAR(); MFMA_Q(1, 1, b1r); BAR();
    // ph3: (mh1,nh0); vmcnt(4) -> tile 2i+1 fully landed
    STAGE_B(0, 1, ktn0);
    WAITVM4(); BAR(); MFMA_Q(1, 0, b0r); BAR();
    // ph4: tile 2i+1 quadrant (mh0,nh0)
    LDA_H(65536, 0); LDB_H(b0r, 65536, 0); STAGE_A(0, 1, ktn0);
    BAR(); MFMA_Q(0, 0, b0r); BAR();
    // ph5: (mh0,nh1)
    LDB_H(b1r, 65536, 1); STAGE_B(0, 0, ktn0);
    BAR(); MFMA_Q(0, 1, b1r); BAR();
    // ph6: (mh1,nh1)
    LDA_H(65536, 1); STAGE_A(65536, 0, ktn1);
    BAR(); MFMA_Q(1, 1, b1r); BAR();
    // ph7: (mh1,nh0); vmcnt(4) -> tile 2i+2 fully landed
    STAGE_B(65536, 1, ktn1);
    WAITVM4(); BAR(); MFMA_Q(1, 0, b0r); BAR();
  }
  WAITVM0();  // drain tail garbage stages before endpgm

  // C/D layout: col = lane&15 (lr), row = kh*4 + j; frag (mg,ng):
  // row = by*256 + wm*128 + mg*16 + kh*4 + j; col = bx*256 + wn*64 + ng*16 + lr
  const long gm0 = (long)by * 256 + wm * 128;
  const long gn0 = (long)bx * 256 + wn * 64;
  if constexpr (EPI == 4) {
    float* C = (float*)Cv + (long)bz * sC;
    const float* R = resid + (long)bz * sR;
#pragma unroll
    for (int mg = 0; mg < 8; ++mg)
#pragma unroll
      for (int ng = 0; ng < 4; ++ng) {
        const long col = gn0 + ng * 16 + lr;
        const float bcol = bias[col];
#pragma unroll
        for (int j = 0; j < 4; ++j) {
          const long row = gm0 + mg * 16 + kh * 4 + j;
          C[row * ldc + col] = acc[mg][ng][j] + bcol + R[row * ldr + col];
        }
      }
  } else {
    unsigned short* C = (unsigned short*)Cv + (long)bz * sC;
#pragma unroll
    for (int mg = 0; mg < 8; ++mg)
#pragma unroll
      for (int ng = 0; ng < 4; ++ng) {
        const long col = gn0 + ng * 16 + lr;
        const float bcol = bias[col];
#pragma unroll
        for (int j = 0; j < 4; ++j) {
          const long row = gm0 + mg * 16 + kh * 4 + j;
          float v = acc[mg][ng][j] + bcol;
          if constexpr (EPI == 1) v = (v > 0.f) ? (v + 1.f) : expf(v);  // elu+1
          if constexpr (EPI == 3) v = fmaxf(v, 0.f);                    // relu
          C[row * ldc + col] = f2bf(v);
        }
      }
  }
#undef STAGE_A
#undef STAGE_B
#undef LDA_H
#undef LDB_H
#undef MFMA_Q
}

// ---------------------------------------------------------------------------
// gemm_bt (128^2, 2-phase): kept for KV / Mt (grids too small for 256^2).
// ---------------------------------------------------------------------------
template <int EPI>
__global__ __launch_bounds__(256, 2) void gemm_bt_kernel(
    const unsigned short* __restrict__ A, long lda, long sA,
    const unsigned short* __restrict__ B, long ldb, long sB,
    void* __restrict__ Cv, long ldc, long sC,
    const float* __restrict__ bias,
    const float* __restrict__ resid, long ldr, long sR, int K) {
  __shared__ short As[128 * 32];
  __shared__ short Bs[128 * 32];
  const int gx = gridDim.x;
  const int nwg = gx * gridDim.y;
  const int orig = blockIdx.y * gx + blockIdx.x;
  const int cpx = nwg >> 3;
  const int wgid = (orig & 7) * cpx + (orig >> 3);
  const int bx = wgid % gx;
  const int by = wgid / gx;

  const int bz = blockIdx.z;
  const unsigned short* Ab = A + (long)bz * sA + (long)by * 128 * lda;
  const unsigned short* Bb = B + (long)bz * sB + (long)bx * 128 * ldb;
  const int tid = threadIdx.x;
  const int w = tid >> 6, lane = tid & 63;
  const int srow = lane >> 2;
  const int scol = (lane & 3) * 8;
  const int wr = (w >> 1) * 64, wc = (w & 1) * 64;
  const int lr = lane & 15, kh = lane >> 4;

  f32x4 acc[4][4];
#pragma unroll
  for (int m = 0; m < 4; ++m)
#pragma unroll
    for (int n = 0; n < 4; ++n)
#pragma unroll
      for (int j = 0; j < 4; ++j) acc[m][n][j] = 0.f;

  const unsigned short* ga0 = Ab + (long)(w * 16 + srow) * lda + scol;
  const unsigned short* ga1 = Ab + (long)(64 + w * 16 + srow) * lda + scol;
  const unsigned short* gb0 = Bb + (long)(w * 16 + srow) * ldb + scol;
  const unsigned short* gb1 = Bb + (long)(64 + w * 16 + srow) * ldb + scol;
  short* la0 = &As[(w * 16) * 32];
  short* la1 = &As[(64 + w * 16) * 32];
  short* lb0 = &Bs[(w * 16) * 32];
  short* lb1 = &Bs[(64 + w * 16) * 32];

  for (int k0 = 0; k0 < K; k0 += 32) {
    GLD16(ga0 + k0, la0);
    GLD16(ga1 + k0, la1);
    GLD16(gb0 + k0, lb0);
    GLD16(gb1 + k0, lb1);
    __syncthreads();
    short8 af[4], bf[4];
#pragma unroll
    for (int m = 0; m < 4; ++m)
      af[m] = *(const short8*)&As[(wr + m * 16 + lr) * 32 + kh * 8];
#pragma unroll
    for (int n = 0; n < 4; ++n)
      bf[n] = *(const short8*)&Bs[(wc + n * 16 + lr) * 32 + kh * 8];
#pragma unroll
    for (int m = 0; m < 4; ++m)
#pragma unroll
      for (int n = 0; n < 4; ++n)
        acc[m][n] =
            __builtin_amdgcn_mfma_f32_16x16x32_bf16(af[m], bf[n], acc[m][n], 0, 0, 0);
    __syncthreads();
  }

  const long gm0 = (long)by * 128 + wr;
  const long gn0 = (long)bx * 128 + wc;
  unsigned short* C = (unsigned short*)Cv + (long)bz * sC;
#pragma unroll
  for (int m = 0; m < 4; ++m)
#pragma unroll
    for (int n = 0; n < 4; ++n) {
      const long col = gn0 + n * 16 + lr;
#pragma unroll
      for (int j = 0; j < 4; ++j) {
        const long row = gm0 + m * 16 + kh * 4 + j;
        C[row * ldc + col] = f2bf(acc[m][n][j]);
      }
    }
}

// ---------------------------------------------------------------------------
// transpose: in flat [S][B][D] bf16 -> out [B][D][S] bf16.
// ---------------------------------------------------------------------------
__global__ __launch_bounds__(256) void transpose_kernel(
    const unsigned short* __restrict__ in, unsigned short* __restrict__ out) {
  __shared__ unsigned short t[64][68];
  const int b = blockIdx.z;
  const long s0 = (long)blockIdx.x * 64, d0 = (long)blockIdx.y * 64;
  const int tid = threadIdx.x;
  {
    const int r = tid >> 3, c = (tid & 7) * 8;
#pragma unroll
    for (int it = 0; it < 2; ++it) {
      const int s = r + it * 32;
      const unsigned short* g = &in[(s0 + s) * (B_DIM * D_DIM) + (long)b * D_DIM + d0 + c];
      short4_t v0 = *(const short4_t*)g;
      short4_t v1 = *(const short4_t*)(g + 4);
      *(short4_t*)&t[s][c] = v0;
      *(short4_t*)&t[s][c + 4] = v1;
    }
  }
  __syncthreads();
  {
    const int d = tid >> 3, c = (tid & 7) * 8;
#pragma unroll
    for (int it = 0; it < 2; ++it) {
      const int dd = d + it * 32;
      short8 v;
#pragma unroll
      for (int j = 0; j < 8; ++j) v[j] = (short)t[c + j][dd];
      *(short8*)&out[(long)b * ((long)D_DIM * S_DIM) + (d0 + dd) * S_DIM + s0 + c] = v;
    }
  }
}

// ---------------------------------------------------------------------------
// layernorm over last dim (1024).
// ---------------------------------------------------------------------------
template <int WRITE_BF16>
__global__ __launch_bounds__(256) void layernorm_kernel(
    const float* in, float* outf, unsigned short* __restrict__ outb,
    const float* __restrict__ gamma, const float* __restrict__ beta) {
  const long row = blockIdx.x;
  const float* x = in + row * D_DIM;
  const int tid = threadIdx.x;
  const int lane = tid & 63, w = tid >> 6;
  f32x4 v = *(const f32x4*)&x[tid * 4];
  float s = v[0] + v[1] + v[2] + v[3];
  float q = v[0] * v[0] + v[1] * v[1] + v[2] * v[2] + v[3] * v[3];
#pragma unroll
  for (int off = 32; off > 0; off >>= 1) {
    s += __shfl_down(s, off, 64);
    q += __shfl_down(q, off, 64);
  }
  __shared__ float red[8];
  if (lane == 0) { red[w] = s; red[w + 4] = q; }
  __syncthreads();
  s = red[0] + red[1] + red[2] + red[3];
  q = red[4] + red[5] + red[6] + red[7];
  const float mu = s * (1.f / D_DIM);
  const float var = q * (1.f / D_DIM) - mu * mu;
  const float rs = rsqrtf(var + 1e-5f);
  f32x4 g = *(const f32x4*)&gamma[tid * 4];
  f32x4 bb = *(const f32x4*)&beta[tid * 4];
  f32x4 o;
#pragma unroll
  for (int j = 0; j < 4; ++j) o[j] = (v[j] - mu) * rs * g[j] + bb[j];
  *(f32x4*)&outf[row * D_DIM + tid * 4] = o;
  if constexpr (WRITE_BF16) {
    short4_t ob;
#pragma unroll
    for (int j = 0; j < 4; ++j) ob[j] = (short)f2bf(o[j]);
    *(short4_t*)&outb[row * D_DIM + tid * 4] = ob;
  }
}

__global__ __launch_bounds__(256) void cast_kernel(
    const float* __restrict__ in, unsigned short* __restrict__ out, long n) {
  long i = ((long)blockIdx.x * 256 + threadIdx.x) * 8;
  if (i >= n) return;
  f32x4 a = *(const f32x4*)&in[i];
  f32x4 b = *(const f32x4*)&in[i + 4];
  short8 v;
#pragma unroll
  for (int j = 0; j < 4; ++j) v[j] = (short)f2bf(a[j]);
#pragma unroll
  for (int j = 0; j < 4; ++j) v[4 + j] = (short)f2bf(b[j]);
  *(short8*)&out[i] = v;
}

// ---------------------------------------------------------------------------
// Workspace plan (MB offsets; 240 MB peak, identical to round 2):
//   0-8 w1b | 8-16 w2b | 16-80 X (early: Vt 16-48, KVm 48-64, Mt 64-80)
//   80-112 Xb | 112-240 H (early: w*b 112-120, srcb/Kt 120-152, Qb 152-184,
//   Kb 184-216, Vb 216-248; AO fp32 184-248 after Kb/Vb dead)
// ---------------------------------------------------------------------------
extern "C" void kernel_launch(void* const* d_in, const int* in_sizes, int n_in,
                              void* d_out, int out_size, void* d_ws, size_t ws_size,
                              hipStream_t stream) {
  const float* src = (const float*)d_in[0];
  const float* wq  = (const float*)d_in[1];
  const float* bq  = (const float*)d_in[2];
  const float* wk  = (const float*)d_in[3];
  const float* bk  = (const float*)d_in[4];
  const float* wv  = (const float*)d_in[5];
  const float* bv  = (const float*)d_in[6];
  const float* wo  = (const float*)d_in[7];
  const float* bo  = (const float*)d_in[8];
  const float* w1  = (const float*)d_in[9];
  const float* b1  = (const float*)d_in[10];
  const float* w2  = (const float*)d_in[11];
  const float* b2  = (const float*)d_in[12];
  const float* g1  = (const float*)d_in[13];
  const float* be1 = (const float*)d_in[14];
  const float* g2  = (const float*)d_in[15];
  const float* be2 = (const float*)d_in[16];

  const long MB = 1024L * 1024L;
  if (ws_size < 248 * MB) return;
  char* ws = (char*)d_ws;
  unsigned short* w1b  = (unsigned short*)(ws + 0 * MB);
  unsigned short* w2b  = (unsigned short*)(ws + 8 * MB);
  float*          X    = (float*)(ws + 16 * MB);
  unsigned short* Xb   = (unsigned short*)(ws + 80 * MB);
  unsigned short* H    = (unsigned short*)(ws + 112 * MB);
  unsigned short* wqb  = (unsigned short*)(ws + 112 * MB);
  unsigned short* wkb  = (unsigned short*)(ws + 114 * MB);
  unsigned short* wvb  = (unsigned short*)(ws + 116 * MB);
  unsigned short* wob  = (unsigned short*)(ws + 118 * MB);
  unsigned short* srcb = (unsigned short*)(ws + 120 * MB);
  unsigned short* Kt   = (unsigned short*)(ws + 120 * MB);
  unsigned short* Vt   = (unsigned short*)(ws + 16 * MB);
  unsigned short* KVm  = (unsigned short*)(ws + 48 * MB);
  unsigned short* Mt   = (unsigned short*)(ws + 64 * MB);
  unsigned short* Qb   = (unsigned short*)(ws + 152 * MB);
  unsigned short* Kb   = (unsigned short*)(ws + 184 * MB);
  unsigned short* Vb   = (unsigned short*)(ws + 216 * MB);
  float*          AO   = (float*)(ws + 184 * MB);

  const dim3 blk(256);
  const dim3 blk512(512);
  // casts
  cast_kernel<<<dim3(512), blk, 0, stream>>>(wq, wqb, 1048576);
  cast_kernel<<<dim3(512), blk, 0, stream>>>(wk, wkb, 1048576);
  cast_kernel<<<dim3(512), blk, 0, stream>>>(wv, wvb, 1048576);
  cast_kernel<<<dim3(512), blk, 0, stream>>>(wo, wob, 1048576);
  cast_kernel<<<dim3(2048), blk, 0, stream>>>(w1, w1b, 4194304);
  cast_kernel<<<dim3(2048), blk, 0, stream>>>(w2, w2b, 4194304);
  cast_kernel<<<dim3(8192), blk, 0, stream>>>(src, srcb, 16777216);

  // Q/K/V projections: [16384,1024]@[1024,1024]^T, 256^2 tiles (grid 4x64)
  gemm256_kernel<1><<<dim3(4, 64, 1), blk512, 0, stream>>>(
      srcb, 1024, 0, wqb, 1024, 0, Qb, 1024, 0, bq, nullptr, 0, 0, 1024);
  gemm256_kernel<1><<<dim3(4, 64, 1), blk512, 0, stream>>>(
      srcb, 1024, 0, wkb, 1024, 0, Kb, 1024, 0, bk, nullptr, 0, 0, 1024);
  gemm256_kernel<2><<<dim3(4, 64, 1), blk512, 0, stream>>>(
      srcb, 1024, 0, wvb, 1024, 0, Vb, 1024, 0, bv, nullptr, 0, 0, 1024);

  // per-batch transposes -> [B][D][S]
  transpose_kernel<<<dim3(32, 16, 8), blk, 0, stream>>>(Kb, Kt);
  transpose_kernel<<<dim3(32, 16, 8), blk, 0, stream>>>(Vb, Vt);

  // KV[d,f] = sum_s Kt[d,s]*Vt[f,s]  (M=N=1024, K=2048, batch 8) -- 128^2
  gemm_bt_kernel<0><<<dim3(8, 8, 8), blk, 0, stream>>>(
      Kt, 2048, 2097152, Vt, 2048, 2097152, KVm, 1024, 1048576,
      nullptr, nullptr, 0, 0, 2048);
  // Mt[e,d] = sum_f wo[e,f]*KV[d,f]  (M=N=1024, K=1024, batch 8) -- 128^2
  gemm_bt_kernel<0><<<dim3(8, 8, 8), blk, 0, stream>>>(
      wob, 1024, 0, KVm, 1024, 1048576, Mt, 1024, 1048576,
      nullptr, nullptr, 0, 0, 1024);
  // AO[s,b,e] = sum_d Q[s,b,d]*Mt[e,d] + bo[e] + src  (256^2, grid 4x8x8)
  gemm256_kernel<4><<<dim3(4, 8, 8), blk512, 0, stream>>>(
      Qb, 8192, 1024, Mt, 1024, 1048576, AO, 8192, 1024,
      bo, src, 8192, 1024, 1024);

  // x = LN(AO)
  layernorm_kernel<1><<<dim3(16384), blk, 0, stream>>>(AO, X, Xb, g1, be1);

  // FFN, full M=16384, 256^2 tiles
  gemm256_kernel<3><<<dim3(16, 64, 1), blk512, 0, stream>>>(
      Xb, 1024, 0, w1b, 1024, 0, H, 4096, 0, b1, nullptr, 0, 0, 1024);
  gemm256_kernel<4><<<dim3(4, 64, 1), blk512, 0, stream>>>(
      H, 4096, 0, w2b, 4096, 0, (float*)d_out, 1024, 0,
      b2, X, 1024, 0, 4096);

  // final LN in-place on d_out
  layernorm_kernel<0><<<dim3(16384), blk, 0, stream>>>(
      (float*)d_out, (float*)d_out, nullptr, g2, be2);
}